// Round 26
// baseline (126.167 us; speedup 1.0000x reference)
//
#include <hip/hip_runtime.h>
#include <hip/hip_bf16.h>

#define B_  2
#define T_  2048
#define C_  1024
#define H_  16
#define D_  64
#define M_  (B_*T_)   // 4096
#define N1_ (3*C_)    // 3072

typedef short bf16x8 __attribute__((ext_vector_type(8)));
typedef short bf16x4 __attribute__((ext_vector_type(4)));
typedef float f32x4 __attribute__((ext_vector_type(4)));
typedef unsigned short u16;
typedef u16 u16x8 __attribute__((ext_vector_type(8)));

#define QSCALE 0.18033688011112042f   // (1/8) * log2(e)
#define C8     11.541560327111707f    // 8 * log2(e)

__device__ __forceinline__ u16 f2bf(float f) {
  unsigned u = __float_as_uint(f);
  u += 0x7FFFu + ((u >> 16) & 1u);
  return (u16)(u >> 16);
}

__device__ __forceinline__ void gload16(const void* g, void* l) {
  __builtin_amdgcn_global_load_lds((__attribute__((address_space(1))) void*)g,
                                   (__attribute__((address_space(3))) void*)l,
                                   16, 0, 0);
}

// ---------------- fp32 -> bf16 conversion, 3 sources -> contiguous ws ----------------
__global__ __launch_bounds__(256) void cvt3(const float* __restrict__ x,
                                            const float* __restrict__ wa,
                                            const float* __restrict__ wp,
                                            u16* __restrict__ out) {
  int i = (blockIdx.x * 256 + threadIdx.x) * 8;
  const float* src;
  int off;
  if (i < M_ * C_)                 { src = x;  off = 0; }
  else if (i < M_ * C_ + N1_ * C_) { src = wa; off = M_ * C_; }
  else                             { src = wp; off = M_ * C_ + N1_ * C_; }
  float4 a = *(const float4*)(src + (i - off));
  float4 b = *(const float4*)(src + (i - off) + 4);
  u16x8 o;
  o[0] = f2bf(a.x); o[1] = f2bf(a.y); o[2] = f2bf(a.z); o[3] = f2bf(a.w);
  o[4] = f2bf(b.x); o[5] = f2bf(b.y); o[6] = f2bf(b.z); o[7] = f2bf(b.w);
  *(u16x8*)(out + i) = o;
}

// ---------------- GEMM1: qkv = x @ W_attn^T + b; split-K 8-wave blocks ----------------
// 512 threads: wave-group wg (0/1) handles K-chunks kt*64 + wg*32 with its
// own LDS tile pair -> barrier windows halve (8 vs 16) at constant per-window
// MFMA density; 24 waves/CU (vs 12). Exact fp32 combine via two 32KB LDS
// phases; epilogue (bias/scale/scatter, Q pre-scaled by log2e/8) by wg==0.
__global__ __launch_bounds__(512) void gemm_qkv(const u16* __restrict__ A,
                                                const u16* __restrict__ W,
                                                const float* __restrict__ bias,
                                                u16* __restrict__ Qb,
                                                u16* __restrict__ Kb,
                                                u16* __restrict__ Vt) {
  __shared__ __align__(16) u16 As[2][128 * 32];
  __shared__ __align__(16) u16 Bs[2][128 * 32];
  const int K = C_;
  int tid = threadIdx.x;
  int lane = tid & 63, wid = tid >> 6;   // 0..7
  int wg = wid >> 2, w4 = wid & 3;
  int wr = w4 >> 1, wc = w4 & 1;
  int m0 = blockIdx.x * 128, n0 = blockIdx.y * 128;

  int arow = w4 * 16 + (lane >> 2);
  int ag = lane & 3;
  int sg = ag ^ ((arow >> 1) & 3);
  const u16* aSrc0 = A + (size_t)(m0 + arow) * K + wg * 32 + sg * 8;
  const u16* aSrc1 = aSrc0 + (size_t)64 * K;
  const u16* bSrc0 = W + (size_t)(n0 + arow) * K + wg * 32 + sg * 8;
  const u16* bSrc1 = bSrc0 + (size_t)64 * K;
  u16* aDst0 = &As[wg][(w4 * 16) * 32];
  u16* aDst1 = &As[wg][(64 + w4 * 16) * 32];
  u16* bDst0 = &Bs[wg][(w4 * 16) * 32];
  u16* bDst1 = &Bs[wg][(64 + w4 * 16) * 32];

  int rg = lane >> 4;
  int aoff[4], boff[4];
#pragma unroll
  for (int m = 0; m < 4; ++m) {
    int row = wr * 64 + m * 16 + (lane & 15);
    aoff[m] = row * 32 + (rg ^ ((row >> 1) & 3)) * 8;
    row = wc * 64 + m * 16 + (lane & 15);
    boff[m] = row * 32 + (rg ^ ((row >> 1) & 3)) * 8;
  }

  f32x4 acc[4][4] = {};
  for (int kt = 0; kt < K / 64; ++kt) {
    int k0 = kt * 64;
    __syncthreads();
    gload16(aSrc0 + k0, aDst0);
    gload16(aSrc1 + k0, aDst1);
    gload16(bSrc0 + k0, bDst0);
    gload16(bSrc1 + k0, bDst1);
    __syncthreads();

    bf16x8 af[4], bfr[4];
#pragma unroll
    for (int m = 0; m < 4; ++m) af[m] = *(const bf16x8*)(&As[wg][0] + aoff[m]);
#pragma unroll
    for (int n = 0; n < 4; ++n) bfr[n] = *(const bf16x8*)(&Bs[wg][0] + boff[n]);
#pragma unroll
    for (int m = 0; m < 4; ++m)
#pragma unroll
      for (int n = 0; n < 4; ++n)
        acc[m][n] = __builtin_amdgcn_mfma_f32_16x16x32_bf16(af[m], bfr[n], acc[m][n], 0, 0, 0);
  }

  // combine: wg==1 publishes acc in two 32KB LDS phases; wg==0 adds
  f32x4* Sc = (f32x4*)&As[0][0];        // 32KB = 2048 f32x4
  __syncthreads();
#pragma unroll
  for (int p = 0; p < 2; ++p) {
    if (wg == 1 && wr == p) {
#pragma unroll
      for (int m = 0; m < 4; ++m)
#pragma unroll
        for (int n = 0; n < 4; ++n)
          Sc[(wc * 64 + lane) * 16 + m * 4 + n] = acc[m][n];
    }
    __syncthreads();
    if (wg == 0 && wr == p) {
#pragma unroll
      for (int m = 0; m < 4; ++m)
#pragma unroll
        for (int n = 0; n < 4; ++n)
          acc[m][n] += Sc[(wc * 64 + lane) * 16 + m * 4 + n];
    }
    __syncthreads();
  }

  if (wg != 0) return;
  int cl = lane & 15;
#pragma unroll
  for (int n = 0; n < 4; ++n) {
    int gn = n0 + wc * 64 + n * 16 + cl;
    float bv = bias[gn];
    int seg = gn >> 10, cc = gn & 1023;
    int h = cc >> 6, d = cc & 63;
    float sc2 = (seg == 0) ? QSCALE : 1.0f;
#pragma unroll
    for (int m = 0; m < 4; ++m) {
#pragma unroll
      for (int r = 0; r < 4; ++r) {
        int gm = m0 + wr * 64 + m * 16 + rg * 4 + r;
        int b = gm >> 11, t = gm & 2047;
        u16 val = f2bf((acc[m][n][r] + bv) * sc2);
        int bh = b * 16 + h;
        if (seg == 0)      Qb[((size_t)(bh * 2048 + t)) * 64 + d] = val;
        else if (seg == 1) Kb[((size_t)(bh * 2048 + t)) * 64 + d] = val;
        else               Vt[((size_t)(bh * 64 + d)) * 2048 + t] = val;
      }
    }
  }
}

// ---------------- GEMM mainloop, 128x64, BK=32 (best for proj: 2 blocks/CU) ----------
__device__ __forceinline__ void gemm_core64(const u16* __restrict__ A,
                                            const u16* __restrict__ W,
                                            u16* As, u16* Bs,
                                            f32x4 (&acc)[4][2],
                                            int m0, int n0, int K) {
  int tid = threadIdx.x;
  int lane = tid & 63, wid = tid >> 6;
  int wr = wid >> 1, wc = wid & 1;

  int arow = wid * 16 + (lane >> 2);
  int ag = lane & 3;
  int sg = ag ^ ((arow >> 1) & 3);
  const u16* aSrc0 = A + (size_t)(m0 + arow) * K + sg * 8;
  const u16* aSrc1 = aSrc0 + (size_t)64 * K;
  const u16* bSrc  = W + (size_t)(n0 + arow) * K + sg * 8;
  u16* aDst0 = As + (wid * 16) * 32;
  u16* aDst1 = As + (64 + wid * 16) * 32;
  u16* bDst  = Bs + (wid * 16) * 32;

  int rg = lane >> 4;
  int aoff[4], boff[2];
#pragma unroll
  for (int m = 0; m < 4; ++m) {
    int row = wr * 64 + m * 16 + (lane & 15);
    aoff[m] = row * 32 + (rg ^ ((row >> 1) & 3)) * 8;
  }
#pragma unroll
  for (int n = 0; n < 2; ++n) {
    int row = wc * 32 + n * 16 + (lane & 15);
    boff[n] = row * 32 + (rg ^ ((row >> 1) & 3)) * 8;
  }

  for (int kt = 0; kt < K / 32; ++kt) {
    int k0 = kt * 32;
    __syncthreads();
    gload16(aSrc0 + k0, aDst0);
    gload16(aSrc1 + k0, aDst1);
    gload16(bSrc + k0, bDst);
    __syncthreads();

    bf16x8 af[4], bfr[2];
#pragma unroll
    for (int m = 0; m < 4; ++m) af[m] = *(const bf16x8*)(As + aoff[m]);
#pragma unroll
    for (int n = 0; n < 2; ++n) bfr[n] = *(const bf16x8*)(Bs + boff[n]);
#pragma unroll
    for (int m = 0; m < 4; ++m)
#pragma unroll
      for (int n = 0; n < 2; ++n)
        acc[m][n] = __builtin_amdgcn_mfma_f32_16x16x32_bf16(af[m], bfr[n], acc[m][n], 0, 0, 0);
  }
}

// ---------------- GEMM2 (BN=64): out = y @ W_proj^T + b ----------------
__global__ __launch_bounds__(256) void gemm_proj(const u16* __restrict__ A,
                                                 const u16* __restrict__ W,
                                                 const float* __restrict__ bias,
                                                 float* __restrict__ out) {
  __shared__ __align__(16) u16 As[128 * 32];
  __shared__ __align__(16) u16 Bs[64 * 32];
  f32x4 acc[4][2] = {};
  int m0 = blockIdx.x * 128, n0 = blockIdx.y * 64;
  gemm_core64(A, W, As, Bs, acc, m0, n0, C_);

  int lane = threadIdx.x & 63, wid = threadIdx.x >> 6;
  int wr = wid >> 1, wc = wid & 1;
  int rg = lane >> 4, cl = lane & 15;
#pragma unroll
  for (int n = 0; n < 2; ++n) {
    int gn = n0 + wc * 32 + n * 16 + cl;
    float bv = bias[gn];
#pragma unroll
    for (int m = 0; m < 4; ++m) {
#pragma unroll
      for (int r = 0; r < 4; ++r) {
        int gm = m0 + wr * 64 + m * 16 + rg * 4 + r;
        out[(size_t)gm * 1024 + gn] = acc[m][n][r] + bv;
      }
    }
  }
}

// ---------------- flash attention v20: 8-wave shared staging + kv-split (unchanged) ----
__global__ __launch_bounds__(512, 2) void attn_fwd(const u16* __restrict__ Qb,
                                                   const u16* __restrict__ Kb,
                                                   const u16* __restrict__ Vt,
                                                   u16* __restrict__ Yb) {
  __shared__ __align__(16) u16 Ks[2][64 * 64];
  __shared__ __align__(16) u16 Vs[2][64 * 64];
  __shared__ __align__(16) u16 Ps[8][32 * 32];
  int tid = threadIdx.x, lane = tid & 63, w = tid >> 6;
  int w4 = w >> 1, kvh = w & 1;
  int cl = lane & 15, kg = lane >> 4;
  int sw = (cl ^ (cl >> 2)) & 3;
  int bid = blockIdx.x;
  int bh = bid & 31;
  int i = bid >> 5;
  int qt = (i < 8) ? i : 23 - i;
  int qb0 = qt * 128 + w4 * 32;
  int jmaxw = (qb0 + 31) >> 6;
  int jmaxb = 2 * qt + 1;
  bool hasHigh = (qb0 & 32) != 0;
  const u16* Qp = Qb + (size_t)bh * (2048 * 64);
  const u16* Kp = Kb + (size_t)bh * (2048 * 64);
  const u16* Vp = Vt + (size_t)bh * (64 * 2048);
  u16* Pw = Ps[w];

  int srow8 = lane >> 3;
  int sg = (lane & 7) ^ srow8;
  const u16* Ksrc = Kp + (w * 8 + srow8) * 64 + sg * 8;
  const u16* Vsrc = Vp + (w * 8 + srow8) * 2048 + sg * 8;

  bf16x8 qf[2][2];
#pragma unroll
  for (int fr = 0; fr < 2; ++fr)
#pragma unroll
    for (int dk = 0; dk < 2; ++dk)
      qf[fr][dk] = *(const bf16x8*)(Qp + (qb0 + fr * 16 + cl) * 64 + dk * 32 + kg * 8);

  f32x4 o[2][4] = {};
  float lsum[2] = {0.f, 0.f};
  const f32x4 CINIT = {-C8, -C8, -C8, -C8};

  auto STAGE = [&](int j, int buf) {
    gload16(Ksrc + j * 4096, &Ks[buf][w * 512]);
    gload16(Vsrc + j * 64, &Vs[buf][w * 512]);
  };

  auto CORE = [&](int buf, int j, bool mask) {
    const u16* Kl = Ks[buf];
    const u16* Vl = Vs[buf];
    bf16x8 kf[2][2];
#pragma unroll
    for (int fcl = 0; fcl < 2; ++fcl) {
      int row = (kvh * 2 + fcl) * 16 + cl;
      kf[fcl][0] = *(const bf16x8*)(Kl + row * 64 + ((kg ^ (cl & 7)) * 8));
      kf[fcl][1] = *(const bf16x8*)(Kl + row * 64 + (((4 + kg) ^ (cl & 7)) * 8));
    }
    bf16x8 vf[4];
#pragma unroll
    for (int dc = 0; dc < 4; ++dc) {
      int row = dc * 16 + cl;
      vf[dc] = *(const bf16x8*)(Vl + row * 64 + (((kvh * 4 + kg) ^ (cl & 7)) * 8));
    }
    f32x4 s[2][2];
#pragma unroll
    for (int fcl = 0; fcl < 2; ++fcl)
#pragma unroll
      for (int fr = 0; fr < 2; ++fr) {
        f32x4 z = CINIT;
        z = __builtin_amdgcn_mfma_f32_16x16x32_bf16(kf[fcl][0], qf[fr][0], z, 0, 0, 0);
        z = __builtin_amdgcn_mfma_f32_16x16x32_bf16(kf[fcl][1], qf[fr][1], z, 0, 0, 0);
        s[fr][fcl] = z;
      }
    if (mask) {
#pragma unroll
      for (int fr = 0; fr < 2; ++fr) {
        int qg = qb0 + fr * 16 + cl;
#pragma unroll
        for (int fcl = 0; fcl < 2; ++fcl)
#pragma unroll
          for (int r = 0; r < 4; ++r)
            if (j * 64 + (kvh * 2 + fcl) * 16 + kg * 4 + r > qg) s[fr][fcl][r] = -1e30f;
      }
    }
#pragma unroll
    for (int fr = 0; fr < 2; ++fr) {
      int rowb = (fr * 16 + cl) * 32;
#pragma unroll
      for (int fcl = 0; fcl < 2; ++fcl) {
        float p0 = exp2f(s[fr][fcl][0]);
        float p1 = exp2f(s[fr][fcl][1]);
        float p2 = exp2f(s[fr][fcl][2]);
        float p3 = exp2f(s[fr][fcl][3]);
        lsum[fr] += (p0 + p1) + (p2 + p3);
        union { bf16x4 v; __hip_bfloat162 h[2]; } pk;
        pk.h[0] = __float22bfloat162_rn(make_float2(p0, p1));
        pk.h[1] = __float22bfloat162_rn(make_float2(p2, p3));
        *(bf16x4*)(Pw + rowb + (((fcl * 2 + (kg >> 1)) ^ sw) * 8) + (kg & 1) * 4) = pk.v;
      }
    }
    bf16x8 pf[2];
#pragma unroll
    for (int fr = 0; fr < 2; ++fr)
      pf[fr] = *(const bf16x8*)(Pw + (fr * 16 + cl) * 32 + ((kg ^ sw) * 8));
#pragma unroll
    for (int fr = 0; fr < 2; ++fr)
#pragma unroll
      for (int dc = 0; dc < 4; ++dc)
        o[fr][dc] = __builtin_amdgcn_mfma_f32_16x16x32_bf16(pf[fr], vf[dc], o[fr][dc], 0, 0, 0);
  };

  STAGE(0, 0);
  __syncthreads();
  int buf = 0;
  for (int j = 0; j <= jmaxb; ++j) {
    if (j < jmaxb) STAGE(j + 1, buf ^ 1);
    if (j < jmaxw)       CORE(buf, j, false);
    else if (j == jmaxw && (kvh == 0 || hasHigh)) CORE(buf, j, true);
    __syncthreads();
    buf ^= 1;
  }

  f32x4* Co = (f32x4*)((w4 < 2) ? (void*)&Ks[0][0] : (void*)&Vs[0][0]) + (w4 & 1) * 512;
  float*  Cl = (float*)&Ps[0][0] + w4 * 128;
  if (kvh == 1) {
#pragma unroll
    for (int fr = 0; fr < 2; ++fr) {
      Cl[fr * 64 + lane] = lsum[fr];
#pragma unroll
      for (int dc = 0; dc < 4; ++dc) Co[(fr * 4 + dc) * 64 + lane] = o[fr][dc];
    }
  }
  __syncthreads();
  if (kvh == 0) {
    int b = bh >> 4, h = bh & 15;
#pragma unroll
    for (int fr = 0; fr < 2; ++fr) {
      float l = lsum[fr] + Cl[fr * 64 + lane];
#pragma unroll
      for (int dc = 0; dc < 4; ++dc) o[fr][dc] += Co[(fr * 4 + dc) * 64 + lane];
      l += __shfl_xor(l, 16);
      l += __shfl_xor(l, 32);
      float linv = 1.f / l;
      float li[4];
#pragma unroll
      for (int r = 0; r < 4; ++r) li[r] = __shfl(linv, kg * 4 + r);
#pragma unroll
      for (int dc = 0; dc < 4; ++dc)
#pragma unroll
        for (int r = 0; r < 4; ++r) {
          int t = qb0 + fr * 16 + kg * 4 + r;
          int d = dc * 16 + cl;
          Yb[((size_t)(b * 2048 + t)) * 1024 + h * 64 + d] = f2bf(o[fr][dc][r] * li[r]);
        }
    }
  }
}

extern "C" void kernel_launch(void* const* d_in, const int* in_sizes, int n_in,
                              void* d_out, int out_size, void* d_ws, size_t ws_size,
                              hipStream_t stream) {
  const float* x  = (const float*)d_in[0];
  const float* Wa = (const float*)d_in[1];
  const float* ba = (const float*)d_in[2];
  const float* Wp = (const float*)d_in[3];
  const float* bp = (const float*)d_in[4];
  float* out = (float*)d_out;

  u16* xb  = (u16*)d_ws;
  u16* Wab = xb  + (size_t)M_ * C_;
  u16* Wpb = Wab + (size_t)N1_ * C_;
  u16* Qb  = Wpb + (size_t)C_ * C_;
  u16* Kb  = Qb  + (size_t)M_ * C_;
  u16* Vt  = Kb  + (size_t)M_ * C_;
  u16* Yb  = Vt  + (size_t)M_ * C_;

  cvt3<<<(M_ * C_ + N1_ * C_ + C_ * C_) / 2048, 256, 0, stream>>>(x, Wa, Wp, xb);
  gemm_qkv<<<dim3(M_ / 128, N1_ / 128), 512, 0, stream>>>(xb, Wab, ba, Qb, Kb, Vt);
  attn_fwd<<<512, 512, 0, stream>>>(Qb, Kb, Vt, Yb);
  gemm_proj<<<dim3(M_ / 128, C_ / 64), 256, 0, stream>>>(Yb, Wpb, bp, out);
}

// Round 27
// 115.276 us; speedup vs baseline: 1.0945x; 1.0945x over previous
//
#include <hip/hip_runtime.h>
#include <hip/hip_bf16.h>

#define B_  2
#define T_  2048
#define C_  1024
#define H_  16
#define D_  64
#define M_  (B_*T_)   // 4096
#define N1_ (3*C_)    // 3072

typedef short bf16x8 __attribute__((ext_vector_type(8)));
typedef short bf16x4 __attribute__((ext_vector_type(4)));
typedef float f32x4 __attribute__((ext_vector_type(4)));
typedef unsigned short u16;
typedef u16 u16x8 __attribute__((ext_vector_type(8)));

#define QSCALE 0.18033688011112042f   // (1/8) * log2(e)
#define C8     11.541560327111707f    // 8 * log2(e)

__device__ __forceinline__ u16 f2bf(float f) {
  unsigned u = __float_as_uint(f);
  u += 0x7FFFu + ((u >> 16) & 1u);
  return (u16)(u >> 16);
}

__device__ __forceinline__ void gload16(const void* g, void* l) {
  __builtin_amdgcn_global_load_lds((__attribute__((address_space(1))) void*)g,
                                   (__attribute__((address_space(3))) void*)l,
                                   16, 0, 0);
}

// ---------------- fp32 -> bf16 conversion, 3 sources -> contiguous ws ----------------
__global__ __launch_bounds__(256) void cvt3(const float* __restrict__ x,
                                            const float* __restrict__ wa,
                                            const float* __restrict__ wp,
                                            u16* __restrict__ out) {
  int i = (blockIdx.x * 256 + threadIdx.x) * 8;
  const float* src;
  int off;
  if (i < M_ * C_)                 { src = x;  off = 0; }
  else if (i < M_ * C_ + N1_ * C_) { src = wa; off = M_ * C_; }
  else                             { src = wp; off = M_ * C_ + N1_ * C_; }
  float4 a = *(const float4*)(src + (i - off));
  float4 b = *(const float4*)(src + (i - off) + 4);
  u16x8 o;
  o[0] = f2bf(a.x); o[1] = f2bf(a.y); o[2] = f2bf(a.z); o[3] = f2bf(a.w);
  o[4] = f2bf(b.x); o[5] = f2bf(b.y); o[6] = f2bf(b.z); o[7] = f2bf(b.w);
  *(u16x8*)(out + i) = o;
}

// ---------------- GEMM mainloop, 128x128, BK=32 (R19 proven, best for qkv) ----------
__device__ __forceinline__ void gemm_core(const u16* __restrict__ A,
                                          const u16* __restrict__ W,
                                          u16* As, u16* Bs,
                                          f32x4 (&acc)[4][4],
                                          int m0, int n0, int K) {
  int tid = threadIdx.x;
  int lane = tid & 63, wid = tid >> 6;
  int wr = wid >> 1, wc = wid & 1;

  int arow = wid * 16 + (lane >> 2);
  int ag = lane & 3;
  int sg = ag ^ ((arow >> 1) & 3);
  const u16* aSrc0 = A + (size_t)(m0 + arow) * K + sg * 8;
  const u16* aSrc1 = aSrc0 + (size_t)64 * K;
  const u16* bSrc0 = W + (size_t)(n0 + arow) * K + sg * 8;
  const u16* bSrc1 = bSrc0 + (size_t)64 * K;
  u16* aDst0 = As + (wid * 16) * 32;
  u16* aDst1 = As + (64 + wid * 16) * 32;
  u16* bDst0 = Bs + (wid * 16) * 32;
  u16* bDst1 = Bs + (64 + wid * 16) * 32;

  int rg = lane >> 4;
  int aoff[4], boff[4];
#pragma unroll
  for (int m = 0; m < 4; ++m) {
    int row = wr * 64 + m * 16 + (lane & 15);
    aoff[m] = row * 32 + (rg ^ ((row >> 1) & 3)) * 8;
    row = wc * 64 + m * 16 + (lane & 15);
    boff[m] = row * 32 + (rg ^ ((row >> 1) & 3)) * 8;
  }

  for (int kt = 0; kt < K / 32; ++kt) {
    int k0 = kt * 32;
    __syncthreads();
    gload16(aSrc0 + k0, aDst0);
    gload16(aSrc1 + k0, aDst1);
    gload16(bSrc0 + k0, bDst0);
    gload16(bSrc1 + k0, bDst1);
    __syncthreads();

    bf16x8 af[4], bfr[4];
#pragma unroll
    for (int m = 0; m < 4; ++m) af[m] = *(const bf16x8*)(As + aoff[m]);
#pragma unroll
    for (int n = 0; n < 4; ++n) bfr[n] = *(const bf16x8*)(Bs + boff[n]);
#pragma unroll
    for (int m = 0; m < 4; ++m)
#pragma unroll
      for (int n = 0; n < 4; ++n)
        acc[m][n] = __builtin_amdgcn_mfma_f32_16x16x32_bf16(af[m], bfr[n], acc[m][n], 0, 0, 0);
  }
}

// ---------------- GEMM mainloop, 128x64, BK=32 (best for proj: 2 blocks/CU) ----------
__device__ __forceinline__ void gemm_core64(const u16* __restrict__ A,
                                            const u16* __restrict__ W,
                                            u16* As, u16* Bs,
                                            f32x4 (&acc)[4][2],
                                            int m0, int n0, int K) {
  int tid = threadIdx.x;
  int lane = tid & 63, wid = tid >> 6;
  int wr = wid >> 1, wc = wid & 1;

  int arow = wid * 16 + (lane >> 2);
  int ag = lane & 3;
  int sg = ag ^ ((arow >> 1) & 3);
  const u16* aSrc0 = A + (size_t)(m0 + arow) * K + sg * 8;
  const u16* aSrc1 = aSrc0 + (size_t)64 * K;
  const u16* bSrc  = W + (size_t)(n0 + arow) * K + sg * 8;
  u16* aDst0 = As + (wid * 16) * 32;
  u16* aDst1 = As + (64 + wid * 16) * 32;
  u16* bDst  = Bs + (wid * 16) * 32;

  int rg = lane >> 4;
  int aoff[4], boff[2];
#pragma unroll
  for (int m = 0; m < 4; ++m) {
    int row = wr * 64 + m * 16 + (lane & 15);
    aoff[m] = row * 32 + (rg ^ ((row >> 1) & 3)) * 8;
  }
#pragma unroll
  for (int n = 0; n < 2; ++n) {
    int row = wc * 32 + n * 16 + (lane & 15);
    boff[n] = row * 32 + (rg ^ ((row >> 1) & 3)) * 8;
  }

  for (int kt = 0; kt < K / 32; ++kt) {
    int k0 = kt * 32;
    __syncthreads();
    gload16(aSrc0 + k0, aDst0);
    gload16(aSrc1 + k0, aDst1);
    gload16(bSrc + k0, bDst);
    __syncthreads();

    bf16x8 af[4], bfr[2];
#pragma unroll
    for (int m = 0; m < 4; ++m) af[m] = *(const bf16x8*)(As + aoff[m]);
#pragma unroll
    for (int n = 0; n < 2; ++n) bfr[n] = *(const bf16x8*)(Bs + boff[n]);
#pragma unroll
    for (int m = 0; m < 4; ++m)
#pragma unroll
      for (int n = 0; n < 2; ++n)
        acc[m][n] = __builtin_amdgcn_mfma_f32_16x16x32_bf16(af[m], bfr[n], acc[m][n], 0, 0, 0);
  }
}

// ---------------- GEMM1 (R19 core + XCD swizzle): qkv = x @ W_attn^T + b -------------
// Grid 768 (1D, %8==0): bijective swz=(bid&7)*96+(bid>>3); m-major per XCD
// (4 contiguous m-rows/XCD -> 1MB of A stays L2-resident, reused 24x).
__global__ __launch_bounds__(256) void gemm_qkv(const u16* __restrict__ A,
                                                const u16* __restrict__ W,
                                                const float* __restrict__ bias,
                                                u16* __restrict__ Qb,
                                                u16* __restrict__ Kb,
                                                u16* __restrict__ Vt) {
  __shared__ __align__(16) u16 As[128 * 32];
  __shared__ __align__(16) u16 Bs[128 * 32];
  f32x4 acc[4][4] = {};
  int bid = blockIdx.x;
  int swz = (bid & 7) * 96 + (bid >> 3);
  int m0 = (swz / 24) * 128, n0 = (swz % 24) * 128;
  gemm_core(A, W, As, Bs, acc, m0, n0, C_);

  int lane = threadIdx.x & 63, wid = threadIdx.x >> 6;
  int wr = wid >> 1, wc = wid & 1;
  int rg = lane >> 4, cl = lane & 15;
#pragma unroll
  for (int n = 0; n < 4; ++n) {
    int gn = n0 + wc * 64 + n * 16 + cl;
    float bv = bias[gn];
    int seg = gn >> 10, cc = gn & 1023;
    int h = cc >> 6, d = cc & 63;
    float sc = (seg == 0) ? QSCALE : 1.0f;
#pragma unroll
    for (int m = 0; m < 4; ++m) {
#pragma unroll
      for (int r = 0; r < 4; ++r) {
        int gm = m0 + wr * 64 + m * 16 + rg * 4 + r;
        int b = gm >> 11, t = gm & 2047;
        u16 val = f2bf((acc[m][n][r] + bv) * sc);
        int bh = b * 16 + h;
        if (seg == 0)      Qb[((size_t)(bh * 2048 + t)) * 64 + d] = val;
        else if (seg == 1) Kb[((size_t)(bh * 2048 + t)) * 64 + d] = val;
        else               Vt[((size_t)(bh * 64 + d)) * 2048 + t] = val;
      }
    }
  }
}

// ---------------- GEMM2 (BN=64 + XCD swizzle): out = y @ W_proj^T + b ----------------
__global__ __launch_bounds__(256) void gemm_proj(const u16* __restrict__ A,
                                                 const u16* __restrict__ W,
                                                 const float* __restrict__ bias,
                                                 float* __restrict__ out) {
  __shared__ __align__(16) u16 As[128 * 32];
  __shared__ __align__(16) u16 Bs[64 * 32];
  f32x4 acc[4][2] = {};
  int bid = blockIdx.x;
  int swz = (bid & 7) * 64 + (bid >> 3);
  int m0 = (swz / 16) * 128, n0 = (swz % 16) * 64;
  gemm_core64(A, W, As, Bs, acc, m0, n0, C_);

  int lane = threadIdx.x & 63, wid = threadIdx.x >> 6;
  int wr = wid >> 1, wc = wid & 1;
  int rg = lane >> 4, cl = lane & 15;
#pragma unroll
  for (int n = 0; n < 2; ++n) {
    int gn = n0 + wc * 32 + n * 16 + cl;
    float bv = bias[gn];
#pragma unroll
    for (int m = 0; m < 4; ++m) {
#pragma unroll
      for (int r = 0; r < 4; ++r) {
        int gm = m0 + wr * 64 + m * 16 + rg * 4 + r;
        out[(size_t)gm * 1024 + gn] = acc[m][n][r] + bv;
      }
    }
  }
}

// ---------------- flash attention v20: 8-wave shared staging + kv-split (unchanged) ----
__global__ __launch_bounds__(512, 2) void attn_fwd(const u16* __restrict__ Qb,
                                                   const u16* __restrict__ Kb,
                                                   const u16* __restrict__ Vt,
                                                   u16* __restrict__ Yb) {
  __shared__ __align__(16) u16 Ks[2][64 * 64];
  __shared__ __align__(16) u16 Vs[2][64 * 64];
  __shared__ __align__(16) u16 Ps[8][32 * 32];
  int tid = threadIdx.x, lane = tid & 63, w = tid >> 6;
  int w4 = w >> 1, kvh = w & 1;
  int cl = lane & 15, kg = lane >> 4;
  int sw = (cl ^ (cl >> 2)) & 3;
  int bid = blockIdx.x;
  int bh = bid & 31;
  int i = bid >> 5;
  int qt = (i < 8) ? i : 23 - i;
  int qb0 = qt * 128 + w4 * 32;
  int jmaxw = (qb0 + 31) >> 6;
  int jmaxb = 2 * qt + 1;
  bool hasHigh = (qb0 & 32) != 0;
  const u16* Qp = Qb + (size_t)bh * (2048 * 64);
  const u16* Kp = Kb + (size_t)bh * (2048 * 64);
  const u16* Vp = Vt + (size_t)bh * (64 * 2048);
  u16* Pw = Ps[w];

  int srow8 = lane >> 3;
  int sg = (lane & 7) ^ srow8;
  const u16* Ksrc = Kp + (w * 8 + srow8) * 64 + sg * 8;
  const u16* Vsrc = Vp + (w * 8 + srow8) * 2048 + sg * 8;

  bf16x8 qf[2][2];
#pragma unroll
  for (int fr = 0; fr < 2; ++fr)
#pragma unroll
    for (int dk = 0; dk < 2; ++dk)
      qf[fr][dk] = *(const bf16x8*)(Qp + (qb0 + fr * 16 + cl) * 64 + dk * 32 + kg * 8);

  f32x4 o[2][4] = {};
  float lsum[2] = {0.f, 0.f};
  const f32x4 CINIT = {-C8, -C8, -C8, -C8};

  auto STAGE = [&](int j, int buf) {
    gload16(Ksrc + j * 4096, &Ks[buf][w * 512]);
    gload16(Vsrc + j * 64, &Vs[buf][w * 512]);
  };

  auto CORE = [&](int buf, int j, bool mask) {
    const u16* Kl = Ks[buf];
    const u16* Vl = Vs[buf];
    bf16x8 kf[2][2];
#pragma unroll
    for (int fcl = 0; fcl < 2; ++fcl) {
      int row = (kvh * 2 + fcl) * 16 + cl;
      kf[fcl][0] = *(const bf16x8*)(Kl + row * 64 + ((kg ^ (cl & 7)) * 8));
      kf[fcl][1] = *(const bf16x8*)(Kl + row * 64 + (((4 + kg) ^ (cl & 7)) * 8));
    }
    bf16x8 vf[4];
#pragma unroll
    for (int dc = 0; dc < 4; ++dc) {
      int row = dc * 16 + cl;
      vf[dc] = *(const bf16x8*)(Vl + row * 64 + (((kvh * 4 + kg) ^ (cl & 7)) * 8));
    }
    f32x4 s[2][2];
#pragma unroll
    for (int fcl = 0; fcl < 2; ++fcl)
#pragma unroll
      for (int fr = 0; fr < 2; ++fr) {
        f32x4 z = CINIT;
        z = __builtin_amdgcn_mfma_f32_16x16x32_bf16(kf[fcl][0], qf[fr][0], z, 0, 0, 0);
        z = __builtin_amdgcn_mfma_f32_16x16x32_bf16(kf[fcl][1], qf[fr][1], z, 0, 0, 0);
        s[fr][fcl] = z;
      }
    if (mask) {
#pragma unroll
      for (int fr = 0; fr < 2; ++fr) {
        int qg = qb0 + fr * 16 + cl;
#pragma unroll
        for (int fcl = 0; fcl < 2; ++fcl)
#pragma unroll
          for (int r = 0; r < 4; ++r)
            if (j * 64 + (kvh * 2 + fcl) * 16 + kg * 4 + r > qg) s[fr][fcl][r] = -1e30f;
      }
    }
#pragma unroll
    for (int fr = 0; fr < 2; ++fr) {
      int rowb = (fr * 16 + cl) * 32;
#pragma unroll
      for (int fcl = 0; fcl < 2; ++fcl) {
        float p0 = exp2f(s[fr][fcl][0]);
        float p1 = exp2f(s[fr][fcl][1]);
        float p2 = exp2f(s[fr][fcl][2]);
        float p3 = exp2f(s[fr][fcl][3]);
        lsum[fr] += (p0 + p1) + (p2 + p3);
        union { bf16x4 v; __hip_bfloat162 h[2]; } pk;
        pk.h[0] = __float22bfloat162_rn(make_float2(p0, p1));
        pk.h[1] = __float22bfloat162_rn(make_float2(p2, p3));
        *(bf16x4*)(Pw + rowb + (((fcl * 2 + (kg >> 1)) ^ sw) * 8) + (kg & 1) * 4) = pk.v;
      }
    }
    bf16x8 pf[2];
#pragma unroll
    for (int fr = 0; fr < 2; ++fr)
      pf[fr] = *(const bf16x8*)(Pw + (fr * 16 + cl) * 32 + ((kg ^ sw) * 8));
#pragma unroll
    for (int fr = 0; fr < 2; ++fr)
#pragma unroll
      for (int dc = 0; dc < 4; ++dc)
        o[fr][dc] = __builtin_amdgcn_mfma_f32_16x16x32_bf16(pf[fr], vf[dc], o[fr][dc], 0, 0, 0);
  };

  STAGE(0, 0);
  __syncthreads();
  int buf = 0;
  for (int j = 0; j <= jmaxb; ++j) {
    if (j < jmaxb) STAGE(j + 1, buf ^ 1);
    if (j < jmaxw)       CORE(buf, j, false);
    else if (j == jmaxw && (kvh == 0 || hasHigh)) CORE(buf, j, true);
    __syncthreads();
    buf ^= 1;
  }

  f32x4* Co = (f32x4*)((w4 < 2) ? (void*)&Ks[0][0] : (void*)&Vs[0][0]) + (w4 & 1) * 512;
  float*  Cl = (float*)&Ps[0][0] + w4 * 128;
  if (kvh == 1) {
#pragma unroll
    for (int fr = 0; fr < 2; ++fr) {
      Cl[fr * 64 + lane] = lsum[fr];
#pragma unroll
      for (int dc = 0; dc < 4; ++dc) Co[(fr * 4 + dc) * 64 + lane] = o[fr][dc];
    }
  }
  __syncthreads();
  if (kvh == 0) {
    int b = bh >> 4, h = bh & 15;
#pragma unroll
    for (int fr = 0; fr < 2; ++fr) {
      float l = lsum[fr] + Cl[fr * 64 + lane];
#pragma unroll
      for (int dc = 0; dc < 4; ++dc) o[fr][dc] += Co[(fr * 4 + dc) * 64 + lane];
      l += __shfl_xor(l, 16);
      l += __shfl_xor(l, 32);
      float linv = 1.f / l;
      float li[4];
#pragma unroll
      for (int r = 0; r < 4; ++r) li[r] = __shfl(linv, kg * 4 + r);
#pragma unroll
      for (int dc = 0; dc < 4; ++dc)
#pragma unroll
        for (int r = 0; r < 4; ++r) {
          int t = qb0 + fr * 16 + kg * 4 + r;
          int d = dc * 16 + cl;
          Yb[((size_t)(b * 2048 + t)) * 1024 + h * 64 + d] = f2bf(o[fr][dc][r] * li[r]);
        }
    }
  }
}

extern "C" void kernel_launch(void* const* d_in, const int* in_sizes, int n_in,
                              void* d_out, int out_size, void* d_ws, size_t ws_size,
                              hipStream_t stream) {
  const float* x  = (const float*)d_in[0];
  const float* Wa = (const float*)d_in[1];
  const float* ba = (const float*)d_in[2];
  const float* Wp = (const float*)d_in[3];
  const float* bp = (const float*)d_in[4];
  float* out = (float*)d_out;

  u16* xb  = (u16*)d_ws;
  u16* Wab = xb  + (size_t)M_ * C_;
  u16* Wpb = Wab + (size_t)N1_ * C_;
  u16* Qb  = Wpb + (size_t)C_ * C_;
  u16* Kb  = Qb  + (size_t)M_ * C_;
  u16* Vt  = Kb  + (size_t)M_ * C_;
  u16* Yb  = Vt  + (size_t)M_ * C_;

  cvt3<<<(M_ * C_ + N1_ * C_ + C_ * C_) / 2048, 256, 0, stream>>>(x, Wa, Wp, xb);
  gemm_qkv<<<768, 256, 0, stream>>>(xb, Wab, ba, Qb, Kb, Vt);
  attn_fwd<<<512, 512, 0, stream>>>(Qb, Kb, Vt, Yb);
  gemm_proj<<<512, 256, 0, stream>>>(Yb, Wpb, bp, out);
}

// Round 28
// 110.255 us; speedup vs baseline: 1.1443x; 1.0455x over previous
//
#include <hip/hip_runtime.h>
#include <hip/hip_bf16.h>

#define B_  2
#define T_  2048
#define C_  1024
#define H_  16
#define D_  64
#define M_  (B_*T_)   // 4096
#define N1_ (3*C_)    // 3072

typedef short bf16x8 __attribute__((ext_vector_type(8)));
typedef short bf16x4 __attribute__((ext_vector_type(4)));
typedef float f32x4 __attribute__((ext_vector_type(4)));
typedef unsigned short u16;
typedef u16 u16x8 __attribute__((ext_vector_type(8)));

#define QSCALE 0.18033688011112042f   // (1/8) * log2(e)
#define C8     11.541560327111707f    // 8 * log2(e)

__device__ __forceinline__ u16 f2bf(float f) {
  unsigned u = __float_as_uint(f);
  u += 0x7FFFu + ((u >> 16) & 1u);
  return (u16)(u >> 16);
}

__device__ __forceinline__ void gload16(const void* g, void* l) {
  __builtin_amdgcn_global_load_lds((__attribute__((address_space(1))) void*)g,
                                   (__attribute__((address_space(3))) void*)l,
                                   16, 0, 0);
}

// ---------------- fp32 -> bf16 conversion, 3 sources -> contiguous ws ----------------
__global__ __launch_bounds__(256) void cvt3(const float* __restrict__ x,
                                            const float* __restrict__ wa,
                                            const float* __restrict__ wp,
                                            u16* __restrict__ out) {
  int i = (blockIdx.x * 256 + threadIdx.x) * 8;
  const float* src;
  int off;
  if (i < M_ * C_)                 { src = x;  off = 0; }
  else if (i < M_ * C_ + N1_ * C_) { src = wa; off = M_ * C_; }
  else                             { src = wp; off = M_ * C_ + N1_ * C_; }
  float4 a = *(const float4*)(src + (i - off));
  float4 b = *(const float4*)(src + (i - off) + 4);
  u16x8 o;
  o[0] = f2bf(a.x); o[1] = f2bf(a.y); o[2] = f2bf(a.z); o[3] = f2bf(a.w);
  o[4] = f2bf(b.x); o[5] = f2bf(b.y); o[6] = f2bf(b.z); o[7] = f2bf(b.w);
  *(u16x8*)(out + i) = o;
}

// ---------------- GEMM mainloop, 128x128, BK=32 (R19 proven, best for qkv) ----------
__device__ __forceinline__ void gemm_core(const u16* __restrict__ A,
                                          const u16* __restrict__ W,
                                          u16* As, u16* Bs,
                                          f32x4 (&acc)[4][4],
                                          int m0, int n0, int K) {
  int tid = threadIdx.x;
  int lane = tid & 63, wid = tid >> 6;
  int wr = wid >> 1, wc = wid & 1;

  int arow = wid * 16 + (lane >> 2);
  int ag = lane & 3;
  int sg = ag ^ ((arow >> 1) & 3);
  const u16* aSrc0 = A + (size_t)(m0 + arow) * K + sg * 8;
  const u16* aSrc1 = aSrc0 + (size_t)64 * K;
  const u16* bSrc0 = W + (size_t)(n0 + arow) * K + sg * 8;
  const u16* bSrc1 = bSrc0 + (size_t)64 * K;
  u16* aDst0 = As + (wid * 16) * 32;
  u16* aDst1 = As + (64 + wid * 16) * 32;
  u16* bDst0 = Bs + (wid * 16) * 32;
  u16* bDst1 = Bs + (64 + wid * 16) * 32;

  int rg = lane >> 4;
  int aoff[4], boff[4];
#pragma unroll
  for (int m = 0; m < 4; ++m) {
    int row = wr * 64 + m * 16 + (lane & 15);
    aoff[m] = row * 32 + (rg ^ ((row >> 1) & 3)) * 8;
    row = wc * 64 + m * 16 + (lane & 15);
    boff[m] = row * 32 + (rg ^ ((row >> 1) & 3)) * 8;
  }

  for (int kt = 0; kt < K / 32; ++kt) {
    int k0 = kt * 32;
    __syncthreads();
    gload16(aSrc0 + k0, aDst0);
    gload16(aSrc1 + k0, aDst1);
    gload16(bSrc0 + k0, bDst0);
    gload16(bSrc1 + k0, bDst1);
    __syncthreads();

    bf16x8 af[4], bfr[4];
#pragma unroll
    for (int m = 0; m < 4; ++m) af[m] = *(const bf16x8*)(As + aoff[m]);
#pragma unroll
    for (int n = 0; n < 4; ++n) bfr[n] = *(const bf16x8*)(Bs + boff[n]);
#pragma unroll
    for (int m = 0; m < 4; ++m)
#pragma unroll
      for (int n = 0; n < 4; ++n)
        acc[m][n] = __builtin_amdgcn_mfma_f32_16x16x32_bf16(af[m], bfr[n], acc[m][n], 0, 0, 0);
  }
}

// ---------------- GEMM mainloop, 128x64, BK=32 (best for proj: 2 blocks/CU) ----------
__device__ __forceinline__ void gemm_core64(const u16* __restrict__ A,
                                            const u16* __restrict__ W,
                                            u16* As, u16* Bs,
                                            f32x4 (&acc)[4][2],
                                            int m0, int n0, int K) {
  int tid = threadIdx.x;
  int lane = tid & 63, wid = tid >> 6;
  int wr = wid >> 1, wc = wid & 1;

  int arow = wid * 16 + (lane >> 2);
  int ag = lane & 3;
  int sg = ag ^ ((arow >> 1) & 3);
  const u16* aSrc0 = A + (size_t)(m0 + arow) * K + sg * 8;
  const u16* aSrc1 = aSrc0 + (size_t)64 * K;
  const u16* bSrc  = W + (size_t)(n0 + arow) * K + sg * 8;
  u16* aDst0 = As + (wid * 16) * 32;
  u16* aDst1 = As + (64 + wid * 16) * 32;
  u16* bDst  = Bs + (wid * 16) * 32;

  int rg = lane >> 4;
  int aoff[4], boff[2];
#pragma unroll
  for (int m = 0; m < 4; ++m) {
    int row = wr * 64 + m * 16 + (lane & 15);
    aoff[m] = row * 32 + (rg ^ ((row >> 1) & 3)) * 8;
  }
#pragma unroll
  for (int n = 0; n < 2; ++n) {
    int row = wc * 32 + n * 16 + (lane & 15);
    boff[n] = row * 32 + (rg ^ ((row >> 1) & 3)) * 8;
  }

  for (int kt = 0; kt < K / 32; ++kt) {
    int k0 = kt * 32;
    __syncthreads();
    gload16(aSrc0 + k0, aDst0);
    gload16(aSrc1 + k0, aDst1);
    gload16(bSrc + k0, bDst);
    __syncthreads();

    bf16x8 af[4], bfr[2];
#pragma unroll
    for (int m = 0; m < 4; ++m) af[m] = *(const bf16x8*)(As + aoff[m]);
#pragma unroll
    for (int n = 0; n < 2; ++n) bfr[n] = *(const bf16x8*)(Bs + boff[n]);
#pragma unroll
    for (int m = 0; m < 4; ++m)
#pragma unroll
      for (int n = 0; n < 2; ++n)
        acc[m][n] = __builtin_amdgcn_mfma_f32_16x16x32_bf16(af[m], bfr[n], acc[m][n], 0, 0, 0);
  }
}

// ---------------- GEMM1 (R19/R22 exact): qkv = x @ W_attn^T + b ----------------
__global__ __launch_bounds__(256) void gemm_qkv(const u16* __restrict__ A,
                                                const u16* __restrict__ W,
                                                const float* __restrict__ bias,
                                                u16* __restrict__ Qb,
                                                u16* __restrict__ Kb,
                                                u16* __restrict__ Vt) {
  __shared__ __align__(16) u16 As[128 * 32];
  __shared__ __align__(16) u16 Bs[128 * 32];
  f32x4 acc[4][4] = {};
  int m0 = blockIdx.x * 128, n0 = blockIdx.y * 128;
  gemm_core(A, W, As, Bs, acc, m0, n0, C_);

  int lane = threadIdx.x & 63, wid = threadIdx.x >> 6;
  int wr = wid >> 1, wc = wid & 1;
  int rg = lane >> 4, cl = lane & 15;
#pragma unroll
  for (int n = 0; n < 4; ++n) {
    int gn = n0 + wc * 64 + n * 16 + cl;
    float bv = bias[gn];
    int seg = gn >> 10, cc = gn & 1023;
    int h = cc >> 6, d = cc & 63;
    float sc = (seg == 0) ? QSCALE : 1.0f;
#pragma unroll
    for (int m = 0; m < 4; ++m) {
#pragma unroll
      for (int r = 0; r < 4; ++r) {
        int gm = m0 + wr * 64 + m * 16 + rg * 4 + r;
        int b = gm >> 11, t = gm & 2047;
        u16 val = f2bf((acc[m][n][r] + bv) * sc);
        int bh = b * 16 + h;
        if (seg == 0)      Qb[((size_t)(bh * 2048 + t)) * 64 + d] = val;
        else if (seg == 1) Kb[((size_t)(bh * 2048 + t)) * 64 + d] = val;
        else               Vt[((size_t)(bh * 64 + d)) * 2048 + t] = val;
      }
    }
  }
}

// ---------------- GEMM2 (BN=64): out = y @ W_proj^T + b ----------------
__global__ __launch_bounds__(256) void gemm_proj(const u16* __restrict__ A,
                                                 const u16* __restrict__ W,
                                                 const float* __restrict__ bias,
                                                 float* __restrict__ out) {
  __shared__ __align__(16) u16 As[128 * 32];
  __shared__ __align__(16) u16 Bs[64 * 32];
  f32x4 acc[4][2] = {};
  int m0 = blockIdx.x * 128, n0 = blockIdx.y * 64;
  gemm_core64(A, W, As, Bs, acc, m0, n0, C_);

  int lane = threadIdx.x & 63, wid = threadIdx.x >> 6;
  int wr = wid >> 1, wc = wid & 1;
  int rg = lane >> 4, cl = lane & 15;
#pragma unroll
  for (int n = 0; n < 2; ++n) {
    int gn = n0 + wc * 32 + n * 16 + cl;
    float bv = bias[gn];
#pragma unroll
    for (int m = 0; m < 4; ++m) {
#pragma unroll
      for (int r = 0; r < 4; ++r) {
        int gm = m0 + wr * 64 + m * 16 + rg * 4 + r;
        out[(size_t)gm * 1024 + gn] = acc[m][n][r] + bv;
      }
    }
  }
}

// ---------------- flash attention v20: 8-wave shared staging + kv-split ----------------
__global__ __launch_bounds__(512, 2) void attn_fwd(const u16* __restrict__ Qb,
                                                   const u16* __restrict__ Kb,
                                                   const u16* __restrict__ Vt,
                                                   u16* __restrict__ Yb) {
  __shared__ __align__(16) u16 Ks[2][64 * 64];
  __shared__ __align__(16) u16 Vs[2][64 * 64];
  __shared__ __align__(16) u16 Ps[8][32 * 32];
  int tid = threadIdx.x, lane = tid & 63, w = tid >> 6;
  int w4 = w >> 1, kvh = w & 1;
  int cl = lane & 15, kg = lane >> 4;
  int sw = (cl ^ (cl >> 2)) & 3;
  int bid = blockIdx.x;
  int bh = bid & 31;
  int i = bid >> 5;
  int qt = (i < 8) ? i : 23 - i;
  int qb0 = qt * 128 + w4 * 32;
  int jmaxw = (qb0 + 31) >> 6;
  int jmaxb = 2 * qt + 1;
  bool hasHigh = (qb0 & 32) != 0;
  const u16* Qp = Qb + (size_t)bh * (2048 * 64);
  const u16* Kp = Kb + (size_t)bh * (2048 * 64);
  const u16* Vp = Vt + (size_t)bh * (64 * 2048);
  u16* Pw = Ps[w];

  int srow8 = lane >> 3;
  int sg = (lane & 7) ^ srow8;
  const u16* Ksrc = Kp + (w * 8 + srow8) * 64 + sg * 8;
  const u16* Vsrc = Vp + (w * 8 + srow8) * 2048 + sg * 8;

  bf16x8 qf[2][2];
#pragma unroll
  for (int fr = 0; fr < 2; ++fr)
#pragma unroll
    for (int dk = 0; dk < 2; ++dk)
      qf[fr][dk] = *(const bf16x8*)(Qp + (qb0 + fr * 16 + cl) * 64 + dk * 32 + kg * 8);

  f32x4 o[2][4] = {};
  float lsum[2] = {0.f, 0.f};
  const f32x4 CINIT = {-C8, -C8, -C8, -C8};

  auto STAGE = [&](int j, int buf) {
    gload16(Ksrc + j * 4096, &Ks[buf][w * 512]);
    gload16(Vsrc + j * 64, &Vs[buf][w * 512]);
  };

  auto CORE = [&](int buf, int j, bool mask) {
    const u16* Kl = Ks[buf];
    const u16* Vl = Vs[buf];
    bf16x8 kf[2][2];
#pragma unroll
    for (int fcl = 0; fcl < 2; ++fcl) {
      int row = (kvh * 2 + fcl) * 16 + cl;
      kf[fcl][0] = *(const bf16x8*)(Kl + row * 64 + ((kg ^ (cl & 7)) * 8));
      kf[fcl][1] = *(const bf16x8*)(Kl + row * 64 + (((4 + kg) ^ (cl & 7)) * 8));
    }
    bf16x8 vf[4];
#pragma unroll
    for (int dc = 0; dc < 4; ++dc) {
      int row = dc * 16 + cl;
      vf[dc] = *(const bf16x8*)(Vl + row * 64 + (((kvh * 4 + kg) ^ (cl & 7)) * 8));
    }
    f32x4 s[2][2];
#pragma unroll
    for (int fcl = 0; fcl < 2; ++fcl)
#pragma unroll
      for (int fr = 0; fr < 2; ++fr) {
        f32x4 z = CINIT;
        z = __builtin_amdgcn_mfma_f32_16x16x32_bf16(kf[fcl][0], qf[fr][0], z, 0, 0, 0);
        z = __builtin_amdgcn_mfma_f32_16x16x32_bf16(kf[fcl][1], qf[fr][1], z, 0, 0, 0);
        s[fr][fcl] = z;
      }
    if (mask) {
#pragma unroll
      for (int fr = 0; fr < 2; ++fr) {
        int qg = qb0 + fr * 16 + cl;
#pragma unroll
        for (int fcl = 0; fcl < 2; ++fcl)
#pragma unroll
          for (int r = 0; r < 4; ++r)
            if (j * 64 + (kvh * 2 + fcl) * 16 + kg * 4 + r > qg) s[fr][fcl][r] = -1e30f;
      }
    }
#pragma unroll
    for (int fr = 0; fr < 2; ++fr) {
      int rowb = (fr * 16 + cl) * 32;
#pragma unroll
      for (int fcl = 0; fcl < 2; ++fcl) {
        float p0 = exp2f(s[fr][fcl][0]);
        float p1 = exp2f(s[fr][fcl][1]);
        float p2 = exp2f(s[fr][fcl][2]);
        float p3 = exp2f(s[fr][fcl][3]);
        lsum[fr] += (p0 + p1) + (p2 + p3);
        union { bf16x4 v; __hip_bfloat162 h[2]; } pk;
        pk.h[0] = __float22bfloat162_rn(make_float2(p0, p1));
        pk.h[1] = __float22bfloat162_rn(make_float2(p2, p3));
        *(bf16x4*)(Pw + rowb + (((fcl * 2 + (kg >> 1)) ^ sw) * 8) + (kg & 1) * 4) = pk.v;
      }
    }
    bf16x8 pf[2];
#pragma unroll
    for (int fr = 0; fr < 2; ++fr)
      pf[fr] = *(const bf16x8*)(Pw + (fr * 16 + cl) * 32 + ((kg ^ sw) * 8));
#pragma unroll
    for (int fr = 0; fr < 2; ++fr)
#pragma unroll
      for (int dc = 0; dc < 4; ++dc)
        o[fr][dc] = __builtin_amdgcn_mfma_f32_16x16x32_bf16(pf[fr], vf[dc], o[fr][dc], 0, 0, 0);
  };

  STAGE(0, 0);
  __syncthreads();
  int buf = 0;
  for (int j = 0; j <= jmaxb; ++j) {
    if (j < jmaxb) STAGE(j + 1, buf ^ 1);
    if (j < jmaxw)       CORE(buf, j, false);
    else if (j == jmaxw && (kvh == 0 || hasHigh)) CORE(buf, j, true);
    __syncthreads();
    buf ^= 1;
  }

  f32x4* Co = (f32x4*)((w4 < 2) ? (void*)&Ks[0][0] : (void*)&Vs[0][0]) + (w4 & 1) * 512;
  float*  Cl = (float*)&Ps[0][0] + w4 * 128;
  if (kvh == 1) {
#pragma unroll
    for (int fr = 0; fr < 2; ++fr) {
      Cl[fr * 64 + lane] = lsum[fr];
#pragma unroll
      for (int dc = 0; dc < 4; ++dc) Co[(fr * 4 + dc) * 64 + lane] = o[fr][dc];
    }
  }
  __syncthreads();
  if (kvh == 0) {
    int b = bh >> 4, h = bh & 15;
#pragma unroll
    for (int fr = 0; fr < 2; ++fr) {
      float l = lsum[fr] + Cl[fr * 64 + lane];
#pragma unroll
      for (int dc = 0; dc < 4; ++dc) o[fr][dc] += Co[(fr * 4 + dc) * 64 + lane];
      l += __shfl_xor(l, 16);
      l += __shfl_xor(l, 32);
      float linv = 1.f / l;
      float li[4];
#pragma unroll
      for (int r = 0; r < 4; ++r) li[r] = __shfl(linv, kg * 4 + r);
#pragma unroll
      for (int dc = 0; dc < 4; ++dc)
#pragma unroll
        for (int r = 0; r < 4; ++r) {
          int t = qb0 + fr * 16 + kg * 4 + r;
          int d = dc * 16 + cl;
          Yb[((size_t)(b * 2048 + t)) * 1024 + h * 64 + d] = f2bf(o[fr][dc][r] * li[r]);
        }
    }
  }
}

extern "C" void kernel_launch(void* const* d_in, const int* in_sizes, int n_in,
                              void* d_out, int out_size, void* d_ws, size_t ws_size,
                              hipStream_t stream) {
  const float* x  = (const float*)d_in[0];
  const float* Wa = (const float*)d_in[1];
  const float* ba = (const float*)d_in[2];
  const float* Wp = (const float*)d_in[3];
  const float* bp = (const float*)d_in[4];
  float* out = (float*)d_out;

  u16* xb  = (u16*)d_ws;
  u16* Wab = xb  + (size_t)M_ * C_;
  u16* Wpb = Wab + (size_t)N1_ * C_;
  u16* Qb  = Wpb + (size_t)C_ * C_;
  u16* Kb  = Qb  + (size_t)M_ * C_;
  u16* Vt  = Kb  + (size_t)M_ * C_;
  u16* Yb  = Vt  + (size_t)M_ * C_;

  cvt3<<<(M_ * C_ + N1_ * C_ + C_ * C_) / 2048, 256, 0, stream>>>(x, Wa, Wp, xb);
  gemm_qkv<<<dim3(M_ / 128, N1_ / 128), 256, 0, stream>>>(xb, Wab, ba, Qb, Kb, Vt);
  attn_fwd<<<512, 512, 0, stream>>>(Qb, Kb, Vt, Yb);
  gemm_proj<<<dim3(M_ / 128, C_ / 64), 256, 0, stream>>>(Yb, Wpb, bp, out);
}